// Round 3
// baseline (85.120 us; speedup 1.0000x reference)
//
#include <hip/hip_runtime.h>

// InverseDaubechiesWaveletLayer: polyphase inverse DWT (db4), fused.
// in : [B=16, L=16000, 128] f32 (first 64 ch = approx, last 64 = detail)
// out: [B=16, 2L=32000, 64] f32
//
//   out[2m]   = sum_k z_a[m-1+k]*lo[2k+1] + z_d[m-1+k]*hi[2k+1]
//   out[2m+1] = sum_k z_a[m-1+k]*lo[2k]   + z_d[m-1+k]*hi[2k]   (k=0..3)
//
// R3: 4 m-values per thread (sliding window, 7 input rows -> 4 output pairs),
//     nontemporal output stores via clang ext_vector type (R2 used
//     HIP_vector_type, which the builtin rejects).

#define NB 16
#define NL 16000
#define MPT 4              // m-values per thread
#define MBLOCK 64          // m-values per block (16 groups * MPT)
#define NMB (NL / MBLOCK)  // 250 m-blocks per batch

typedef float fx4 __attribute__((ext_vector_type(4)));

__global__ __launch_bounds__(256) void idwt_db4_kernel(
    const float* __restrict__ in,
    const float* __restrict__ rec_lo,
    const float* __restrict__ rec_hi,
    float* __restrict__ out)
{
    const int tid = threadIdx.x;
    const int c  = (tid & 15) * 4;   // channel quad offset 0..60
    const int g  = tid >> 4;         // m-group 0..15
    const int blk = blockIdx.x;
    const int b = blk / NMB;
    const int m0 = (blk - b * NMB) * MBLOCK + g * MPT;

    float lo[8], hi[8];
#pragma unroll
    for (int i = 0; i < 8; ++i) { lo[i] = rec_lo[i]; hi[i] = rec_hi[i]; }

    const long inBase = (long)b * NL * 128 + c;

    // rows m0-1 .. m0+5 (7 rows), approx + detail quads
    fx4 A[MPT + 3], D[MPT + 3];
#pragma unroll
    for (int r = 0; r < MPT + 3; ++r) {
        const int l = m0 - 1 + r;
        if (l >= 0 && l < NL) {
            const fx4* p = (const fx4*)(in + inBase + (long)l * 128);
            A[r] = p[0];    // approx: ch c..c+3
            D[r] = p[16];   // detail: ch 64+c..64+c+3
        } else {
            A[r] = (fx4)(0.f);
            D[r] = (fx4)(0.f);
        }
    }

    const long outBase0 = ((long)b * (2 * NL) + 2 * m0) * 64 + c;

#pragma unroll
    for (int j = 0; j < MPT; ++j) {
        fx4 ev = (fx4)(0.f);
        fx4 od = (fx4)(0.f);
#pragma unroll
        for (int k = 0; k < 4; ++k) {
            const fx4 a = A[j + k], d = D[j + k];
            const float leA = lo[2*k + 1], leD = hi[2*k + 1];  // even-t taps
            const float loA = lo[2*k],     loD = hi[2*k];      // odd-t taps
            ev = a * leA + (d * leD + ev);
            od = a * loA + (d * loD + od);
        }
        float* pe = out + outBase0 + (long)j * 128;       // t = 2(m0+j)
        float* po = pe + 64;                              // t = 2(m0+j)+1
        __builtin_nontemporal_store(ev, (fx4*)pe);
        __builtin_nontemporal_store(od, (fx4*)po);
    }
}

extern "C" void kernel_launch(void* const* d_in, const int* in_sizes, int n_in,
                              void* d_out, int out_size, void* d_ws, size_t ws_size,
                              hipStream_t stream)
{
    const float* in     = (const float*)d_in[0];
    const float* rec_lo = (const float*)d_in[1];
    const float* rec_hi = (const float*)d_in[2];
    float* out = (float*)d_out;

    dim3 grid(NB * NMB);   // 16 * 250 = 4000 blocks
    dim3 block(256);
    idwt_db4_kernel<<<grid, block, 0, stream>>>(in, rec_lo, rec_hi, out);
}

// Round 4
// 54.919 us; speedup vs baseline: 1.5499x; 1.5499x over previous
//
#include <hip/hip_runtime.h>

// InverseDaubechiesWaveletLayer: polyphase inverse DWT (db4), fused.
// in : [B=16, L=16000, 128] f32 (first 64 ch = approx, last 64 = detail)
// out: [B=16, 2L=32000, 64] f32
//
//   out[2m]   = sum_k z_a[m-1+k]*lo[2k+1] + z_d[m-1+k]*hi[2k+1]
//   out[2m+1] = sum_k z_a[m-1+k]*lo[2k]   + z_d[m-1+k]*hi[2k]   (k=0..3)
//
// R4: revert R3's occupancy collapse (192 VGPR, MPT=4, NT stores -> 110us).
//     MPT=2 (5-row window, 10 loads / 2 output pairs), regular stores.

#define NB 16
#define NL 16000
#define MPT 2               // m-values per thread
#define MBLOCK 32           // m-values per block (16 groups * MPT)
#define NMB (NL / MBLOCK)   // 500 m-blocks per batch

typedef float fx4 __attribute__((ext_vector_type(4)));

__global__ __launch_bounds__(256) void idwt_db4_kernel(
    const float* __restrict__ in,
    const float* __restrict__ rec_lo,
    const float* __restrict__ rec_hi,
    float* __restrict__ out)
{
    const int tid = threadIdx.x;
    const int c  = (tid & 15) * 4;   // channel quad offset 0..60
    const int g  = tid >> 4;         // m-group 0..15
    const int blk = blockIdx.x;
    const int b = blk / NMB;
    const int m0 = (blk - b * NMB) * MBLOCK + g * MPT;

    float lo[8], hi[8];
#pragma unroll
    for (int i = 0; i < 8; ++i) { lo[i] = rec_lo[i]; hi[i] = rec_hi[i]; }

    const long inBase = (long)b * NL * 128 + c;

    // rows m0-1 .. m0+3 (5 rows), approx + detail quads
    fx4 A[MPT + 3], D[MPT + 3];
#pragma unroll
    for (int r = 0; r < MPT + 3; ++r) {
        const int l = m0 - 1 + r;
        if (l >= 0 && l < NL) {
            const fx4* p = (const fx4*)(in + inBase + (long)l * 128);
            A[r] = p[0];    // approx: ch c..c+3
            D[r] = p[16];   // detail: ch 64+c..64+c+3
        } else {
            A[r] = (fx4)(0.f);
            D[r] = (fx4)(0.f);
        }
    }

    const long outBase0 = ((long)b * (2 * NL) + 2 * m0) * 64 + c;

#pragma unroll
    for (int j = 0; j < MPT; ++j) {
        fx4 ev = (fx4)(0.f);
        fx4 od = (fx4)(0.f);
#pragma unroll
        for (int k = 0; k < 4; ++k) {
            const fx4 a = A[j + k], d = D[j + k];
            const float leA = lo[2*k + 1], leD = hi[2*k + 1];  // even-t taps
            const float loA = lo[2*k],     loD = hi[2*k];      // odd-t taps
            ev = a * leA + (d * leD + ev);
            od = a * loA + (d * loD + od);
        }
        *(fx4*)(out + outBase0 + (long)j * 128)      = ev;  // t = 2(m0+j)
        *(fx4*)(out + outBase0 + (long)j * 128 + 64) = od;  // t = 2(m0+j)+1
    }
}

extern "C" void kernel_launch(void* const* d_in, const int* in_sizes, int n_in,
                              void* d_out, int out_size, void* d_ws, size_t ws_size,
                              hipStream_t stream)
{
    const float* in     = (const float*)d_in[0];
    const float* rec_lo = (const float*)d_in[1];
    const float* rec_hi = (const float*)d_in[2];
    float* out = (float*)d_out;

    dim3 grid(NB * NMB);   // 16 * 500 = 8000 blocks
    dim3 block(256);
    idwt_db4_kernel<<<grid, block, 0, stream>>>(in, rec_lo, rec_hi, out);
}

// Round 5
// 48.299 us; speedup vs baseline: 1.7623x; 1.1371x over previous
//
#include <hip/hip_runtime.h>

// InverseDaubechiesWaveletLayer: polyphase inverse DWT (db4), fused.
// in : [B=16, L=16000, 128] f32 (first 64 ch = approx, last 64 = detail)
// out: [B=16, 2L=32000, 64] f32
//
//   out[2m]   = sum_k z_a[m-1+k]*lo[2k+1] + z_d[m-1+k]*hi[2k+1]
//   out[2m+1] = sum_k z_a[m-1+k]*lo[2k]   + z_d[m-1+k]*hi[2k]   (k=0..3)
//
// R5: back to R1's 1-m-per-thread mapping (R3/R4 m-tiling = register/occupancy
//     loss, latency-bound). One controlled change vs R1: nontemporal stores —
//     in+out = 262MB > 256MB L3; evict-first writes keep input L3-resident.

#define NB 16
#define NL 16000
#define MBLK 1000   // m-blocks per batch (16 m per block)

typedef float fx4 __attribute__((ext_vector_type(4)));

__global__ __launch_bounds__(256) void idwt_db4_kernel(
    const float* __restrict__ in,
    const float* __restrict__ rec_lo,
    const float* __restrict__ rec_hi,
    float* __restrict__ out)
{
    const int tid = threadIdx.x;
    const int c  = (tid & 15) * 4;   // channel quad offset 0..60
    const int ml = tid >> 4;         // 0..15: m within block
    const int blk = blockIdx.x;
    const int b = blk / MBLK;
    const int m = (blk - b * MBLK) * 16 + ml;

    // Uniform filter loads -> SGPRs (compiler proves uniformity of kernarg).
    float lo[8], hi[8];
#pragma unroll
    for (int i = 0; i < 8; ++i) { lo[i] = rec_lo[i]; hi[i] = rec_hi[i]; }

    const long inBase = (long)b * NL * 128 + c;

    fx4 a[4], d[4];
#pragma unroll
    for (int k = 0; k < 4; ++k) {
        const int l = m - 1 + k;
        if (l >= 0 && l < NL) {
            const fx4* p = (const fx4*)(in + inBase + (long)l * 128);
            a[k] = p[0];    // approx: ch c..c+3
            d[k] = p[16];   // detail: ch 64+c..64+c+3
        } else {
            a[k] = (fx4)(0.f);
            d[k] = (fx4)(0.f);
        }
    }

    fx4 ev = (fx4)(0.f);
    fx4 od = (fx4)(0.f);
#pragma unroll
    for (int k = 0; k < 4; ++k) {
        const float leA = lo[2*k + 1], leD = hi[2*k + 1];   // even-t taps
        const float loA = lo[2*k],     loD = hi[2*k];       // odd-t taps
        ev = a[k] * leA + (d[k] * leD + ev);
        od = a[k] * loA + (d[k] * loD + od);
    }

    const long outBase = ((long)b * (2 * NL) + 2 * m) * 64 + c;
    __builtin_nontemporal_store(ev, (fx4*)(out + outBase));       // t = 2m
    __builtin_nontemporal_store(od, (fx4*)(out + outBase + 64));  // t = 2m+1
}

extern "C" void kernel_launch(void* const* d_in, const int* in_sizes, int n_in,
                              void* d_out, int out_size, void* d_ws, size_t ws_size,
                              hipStream_t stream)
{
    const float* in     = (const float*)d_in[0];
    const float* rec_lo = (const float*)d_in[1];
    const float* rec_hi = (const float*)d_in[2];
    float* out = (float*)d_out;

    dim3 grid(NB * MBLK);   // 16000 blocks
    dim3 block(256);
    idwt_db4_kernel<<<grid, block, 0, stream>>>(in, rec_lo, rec_hi, out);
}